// Round 3
// baseline (437.475 us; speedup 1.0000x reference)
//
#include <hip/hip_runtime.h>
#include <hip/hip_cooperative_groups.h>
#include <math.h>

namespace cg = cooperative_groups;

#define NMAX 4096
#define N4   (NMAX/4)

// n is assumed a multiple of 8 (reference: N=4096).

constexpr float RADIUS       = 0.1f;
constexpr float DT           = 1.0f / 60.0f;
constexpr float MAX_VEL      = 3.0f;               // 0.5*0.1/DT
constexpr float VISCOSITY    = 60.0f;
constexpr float DENSITY_REST = 17510.1f;
constexpr float STIFFNESS    = 2.99e-11f;
constexpr float EPS          = 1e-8f;
constexpr float SPIKY_C      = (float)(15.0 / (3.14159265358979323846 * 1e-6)); // 15/(pi*R^6)

__device__ __forceinline__ float elem(const float4& v, int c) {
    return reinterpret_cast<const float*>(&v)[c];
}

// Single cooperative kernel: predict -> 3x(rho -> delta) -> visc, with grid syncs.
// Block b owns particles [8b, 8b+8); 4 waves/block, 2 particles/wave.
// LDS: 64 KB -> 2 blocks/CU, grid = n/8 = 512 blocks co-resident.
__global__ __launch_bounds__(256) void k_fused(
        const float* __restrict__ locs, const float* __restrict__ vel,
        float* __restrict__ px, float* __restrict__ py, float* __restrict__ pz,
        float* __restrict__ lam,
        float* __restrict__ vnx, float* __restrict__ vny, float* __restrict__ vnz,
        float* __restrict__ out, int n) {
    cg::grid_group grid = cg::this_grid();
    __shared__ float4 smem[4 * N4];   // 64 KB
    float4* sx = smem;
    float4* sy = smem + N4;
    float4* sz = smem + 2 * N4;
    float4* sl = smem + 3 * N4;
    const int tid  = threadIdx.x;
    const int wave = tid >> 6, lane = tid & 63;
    const int i0   = blockIdx.x * 8 + wave * 2;     // first of this wave's 2 particles
    const int n4   = n >> 2;

    // ---------------- predict ----------------
    {
        int i = blockIdx.x * 256 + tid;
        if (i < n) {
            float vx = vel[3*i+0];
            float vy = vel[3*i+1] - 9.8f * DT;
            float vz = vel[3*i+2];
            float vv = sqrtf(vx*vx + vy*vy + vz*vz);
            float s  = fminf(MAX_VEL / (vv + 1e-4f), 1.0f);
            px[i] = locs[3*i+0] + DT * vx * s;
            py[i] = locs[3*i+1] + DT * vy * s;
            pz[i] = locs[3*i+2] + DT * vz * s;
        }
    }
    grid.sync();

    // ---------------- 3 solver iterations ----------------
    for (int it = 0; it < 3; ++it) {
        // stage positions (pre-update; valid for both rho and delta this iter)
        for (int idx = tid; idx < n4; idx += 256) {
            sx[idx] = ((const float4*)px)[idx];
            sy[idx] = ((const float4*)py)[idx];
            sz[idx] = ((const float4*)pz)[idx];
        }
        __syncthreads();

        const float* fx = (const float*)sx; const float* fy = (const float*)sy;
        const float* fz = (const float*)sz; const float* fl = (const float*)sl;
        const float xi0 = fx[i0],   yi0 = fy[i0],   zi0 = fz[i0];
        const float xi1 = fx[i0+1], yi1 = fy[i0+1], zi1 = fz[i0+1];

        // ---- rho: S = sum_j relu(R-d)^3 (self included, subtracted below) ----
        float S0 = 0.f, S1 = 0.f;
        for (int k = lane; k < n4; k += 64) {
            float4 X = sx[k], Y = sy[k], Z = sz[k];
#pragma unroll
            for (int c = 0; c < 4; ++c) {
                float xj = elem(X,c), yj = elem(Y,c), zj = elem(Z,c);
                {
                    float dx = xi0-xj, dy = yi0-yj, dz = zi0-zj;
                    float d2 = fmaf(dx,dx,EPS); d2 = fmaf(dy,dy,d2); d2 = fmaf(dz,dz,d2);
                    float t  = fmaxf(RADIUS - __builtin_amdgcn_sqrtf(d2), 0.f);
                    S0 = fmaf(t*t, t, S0);
                }
                {
                    float dx = xi1-xj, dy = yi1-yj, dz = zi1-zj;
                    float d2 = fmaf(dx,dx,EPS); d2 = fmaf(dy,dy,d2); d2 = fmaf(dz,dz,d2);
                    float t  = fmaxf(RADIUS - __builtin_amdgcn_sqrtf(d2), 0.f);
                    S1 = fmaf(t*t, t, S1);
                }
            }
        }
        for (int off = 32; off > 0; off >>= 1) {
            S0 += __shfl_down(S0, off);
            S1 += __shfl_down(S1, off);
        }
        if (lane == 0) {
            const float ts  = RADIUS - __builtin_amdgcn_sqrtf(EPS);  // exact self-term
            const float TS3 = ts*ts*ts;
            const float k3  = 3.f * SPIKY_C * STIFFNESS;             // L = -3C*lam
            lam[i0]   = k3 * (SPIKY_C * (S0 - TS3) - DENSITY_REST);
            lam[i0+1] = k3 * (SPIKY_C * (S1 - TS3) - DENSITY_REST);
        }
        grid.sync();   // all lam ready

        // stage lam
        for (int idx = tid; idx < n4; idx += 256) sl[idx] = ((const float4*)lam)[idx];
        __syncthreads();

        // ---- delta: pred += sum_j (L_i+L_j) * t^2 / d * diff ----
        const float L0 = fl[i0], L1 = fl[i0+1];
        float ax0=0.f, ay0=0.f, az0=0.f, ax1=0.f, ay1=0.f, az1=0.f;
        for (int k = lane; k < n4; k += 64) {
            float4 X = sx[k], Y = sy[k], Z = sz[k], L = sl[k];
#pragma unroll
            for (int c = 0; c < 4; ++c) {
                float xj = elem(X,c), yj = elem(Y,c), zj = elem(Z,c), Lj = elem(L,c);
                {
                    float dx = xi0-xj, dy = yi0-yj, dz = zi0-zj;
                    float d2 = fmaf(dx,dx,EPS); d2 = fmaf(dy,dy,d2); d2 = fmaf(dz,dz,d2);
                    float rinv = __builtin_amdgcn_rsqf(d2);
                    float t  = fmaxf(RADIUS - d2*rinv, 0.f);
                    float cf = (L0 + Lj) * (t*t) * rinv;
                    ax0 = fmaf(cf, dx, ax0); ay0 = fmaf(cf, dy, ay0); az0 = fmaf(cf, dz, az0);
                }
                {
                    float dx = xi1-xj, dy = yi1-yj, dz = zi1-zj;
                    float d2 = fmaf(dx,dx,EPS); d2 = fmaf(dy,dy,d2); d2 = fmaf(dz,dz,d2);
                    float rinv = __builtin_amdgcn_rsqf(d2);
                    float t  = fmaxf(RADIUS - d2*rinv, 0.f);
                    float cf = (L1 + Lj) * (t*t) * rinv;
                    ax1 = fmaf(cf, dx, ax1); ay1 = fmaf(cf, dy, ay1); az1 = fmaf(cf, dz, az1);
                }
            }
        }
        for (int off = 32; off > 0; off >>= 1) {
            ax0 += __shfl_down(ax0, off); ay0 += __shfl_down(ay0, off); az0 += __shfl_down(az0, off);
            ax1 += __shfl_down(ax1, off); ay1 += __shfl_down(ay1, off); az1 += __shfl_down(az1, off);
        }
        if (lane == 0) {
#pragma unroll
            for (int u = 0; u < 2; ++u) {
                int i = i0 + u;
                float nx_ = (u ? xi1+ax1 : xi0+ax0);
                float ny_ = (u ? yi1+ay1 : yi0+ay0);
                float nz_ = (u ? zi1+az1 : zi0+az0);
                px[i] = nx_; py[i] = ny_; pz[i] = nz_;
                if (it == 2) {
                    out[3*i+0] = nx_; out[3*i+1] = ny_; out[3*i+2] = nz_;
                    vnx[i] = (nx_ - locs[3*i+0]) * (1.0f/DT);
                    vny[i] = (ny_ - locs[3*i+1]) * (1.0f/DT);
                    vnz[i] = (nz_ - locs[3*i+2]) * (1.0f/DT);
                }
            }
        }
        grid.sync();   // all new positions (and, last iter, vn) ready
    }

    // ---------------- XSPH viscosity ----------------
    // reuse LDS as 6 chunk arrays of n/8 float4 each (48 KB)
    const int n8 = n >> 3;
    float4* cx  = smem;            float4* cy  = smem + n8;     float4* cz  = smem + 2*n8;
    float4* cvx = smem + 3*n8;     float4* cvy = smem + 4*n8;   float4* cvz = smem + 5*n8;
    const float Xi0 = px[i0],   Yi0 = py[i0],   Zi0 = pz[i0];
    const float Xi1 = px[i0+1], Yi1 = py[i0+1], Zi1 = pz[i0+1];
    const float vix0 = vnx[i0],   viy0 = vny[i0],   viz0 = vnz[i0];
    const float vix1 = vnx[i0+1], viy1 = vny[i0+1], viz1 = vnz[i0+1];
    float ws0=0.f, ax0=0.f, ay0=0.f, az0=0.f;
    float ws1=0.f, ax1=0.f, ay1=0.f, az1=0.f;
    for (int ch = 0; ch < 2; ++ch) {
        __syncthreads();
        for (int idx = tid; idx < n8; idx += 256) {
            cx[idx]  = ((const float4*)px)[ch*n8+idx];
            cy[idx]  = ((const float4*)py)[ch*n8+idx];
            cz[idx]  = ((const float4*)pz)[ch*n8+idx];
            cvx[idx] = ((const float4*)vnx)[ch*n8+idx];
            cvy[idx] = ((const float4*)vny)[ch*n8+idx];
            cvz[idx] = ((const float4*)vnz)[ch*n8+idx];
        }
        __syncthreads();
        for (int k = lane; k < n8; k += 64) {
            float4 X = cx[k], Y = cy[k], Z = cz[k], VX = cvx[k], VY = cvy[k], VZ = cvz[k];
#pragma unroll
            for (int c = 0; c < 4; ++c) {
                float xj = elem(X,c), yj = elem(Y,c), zj = elem(Z,c);
                float vxj = elem(VX,c), vyj = elem(VY,c), vzj = elem(VZ,c);
                {
                    float dx = Xi0-xj, dy = Yi0-yj, dz = Zi0-zj;
                    float d2 = fmaf(dx,dx,EPS); d2 = fmaf(dy,dy,d2); d2 = fmaf(dz,dz,d2);
                    float t  = fmaxf(RADIUS - __builtin_amdgcn_sqrtf(d2), 0.f);
                    float w  = t*t*t;
                    ws0 += w;
                    ax0 = fmaf(w, vxj, ax0); ay0 = fmaf(w, vyj, ay0); az0 = fmaf(w, vzj, az0);
                }
                {
                    float dx = Xi1-xj, dy = Yi1-yj, dz = Zi1-zj;
                    float d2 = fmaf(dx,dx,EPS); d2 = fmaf(dy,dy,d2); d2 = fmaf(dz,dz,d2);
                    float t  = fmaxf(RADIUS - __builtin_amdgcn_sqrtf(d2), 0.f);
                    float w  = t*t*t;
                    ws1 += w;
                    ax1 = fmaf(w, vxj, ax1); ay1 = fmaf(w, vyj, ay1); az1 = fmaf(w, vzj, az1);
                }
            }
        }
    }
    for (int off = 32; off > 0; off >>= 1) {
        ws0 += __shfl_down(ws0, off); ax0 += __shfl_down(ax0, off);
        ay0 += __shfl_down(ay0, off); az0 += __shfl_down(az0, off);
        ws1 += __shfl_down(ws1, off); ax1 += __shfl_down(ax1, off);
        ay1 += __shfl_down(ay1, off); az1 += __shfl_down(az1, off);
    }
    if (lane == 0) {
        constexpr float K = VISCOSITY * DT / DENSITY_REST;
        const float KC = K * SPIKY_C;   // w accumulated without C; fold here
#pragma unroll
        for (int u = 0; u < 2; ++u) {
            int i = i0 + u;
            float vix = (u ? vix1 : vix0), viy = (u ? viy1 : viy0), viz = (u ? viz1 : viz0);
            float sw  = (u ? ws1 : ws0);
            float sax = (u ? ax1 : ax0), say = (u ? ay1 : ay0), saz = (u ? az1 : az0);
            float nvx = vix + KC * (sax - sw * vix);
            float nvy = viy + KC * (say - sw * viy);
            float nvz = viz + KC * (saz - sw * viz);
            float vv = sqrtf(nvx*nvx + nvy*nvy + nvz*nvz);
            float s  = fminf(MAX_VEL / (vv + 1e-4f), 1.0f);
            out[3*n + 3*i + 0] = nvx * s;
            out[3*n + 3*i + 1] = nvy * s;
            out[3*n + 3*i + 2] = nvz * s;
        }
    }
}

extern "C" void kernel_launch(void* const* d_in, const int* in_sizes, int n_in,
                              void* d_out, int out_size, void* d_ws, size_t ws_size,
                              hipStream_t stream) {
    const float* locs = (const float*)d_in[0];
    const float* vel  = (const float*)d_in[1];
    float* out = (float*)d_out;
    int n = in_sizes[0] / 3;

    float* w = (float*)d_ws;
    float* px  = w;        float* py  = px + n;   float* pz  = py + n;
    float* lam = pz + n;
    float* vnx = lam + n;  float* vny = vnx + n;  float* vnz = vny + n;

    void* args[] = { (void*)&locs, (void*)&vel, (void*)&px, (void*)&py, (void*)&pz,
                     (void*)&lam, (void*)&vnx, (void*)&vny, (void*)&vnz,
                     (void*)&out, (void*)&n };
    hipLaunchCooperativeKernel((const void*)k_fused, dim3(n / 8), dim3(256), args, 0, stream);
}

// Round 4
// 125.799 us; speedup vs baseline: 3.4776x; 3.4776x over previous
//
#include <hip/hip_runtime.h>
#include <math.h>

#define NMAX 4096
#define N4   (NMAX/4)

// n assumed multiple of 8 (reference: N=4096).

constexpr float RADIUS       = 0.1f;
constexpr float DT           = 1.0f / 60.0f;
constexpr float MAX_VEL      = 3.0f;               // 0.5*0.1/DT
constexpr float VISCOSITY    = 60.0f;
constexpr float DENSITY_REST = 17510.1f;
constexpr float STIFFNESS    = 2.99e-11f;
constexpr float EPS          = 1e-8f;
constexpr float SPIKY_C      = (float)(15.0 / (3.14159265358979323846 * 1e-6)); // 15/(pi*R^6)

__device__ __forceinline__ float elem(const float4& v, int c) {
    return reinterpret_cast<const float*>(&v)[c];
}

// Recompute predicted positions for the whole system into LDS (SoA float4).
// Each thread handles 4 consecutive particles (12 floats = 3 aligned float4s).
__device__ __forceinline__ void predict_to_lds(const float4* __restrict__ locs4,
                                               const float4* __restrict__ vel4,
                                               float4* sx, float4* sy, float4* sz,
                                               int n4, int tid, int nthreads) {
    for (int g = tid; g < n4; g += nthreads) {
        float lo[12], ve[12];
        *(float4*)&lo[0] = locs4[3*g];   *(float4*)&lo[4] = locs4[3*g+1]; *(float4*)&lo[8] = locs4[3*g+2];
        *(float4*)&ve[0] = vel4[3*g];    *(float4*)&ve[4] = vel4[3*g+1];  *(float4*)&ve[8] = vel4[3*g+2];
        float X[4], Y[4], Z[4];
#pragma unroll
        for (int p = 0; p < 4; ++p) {
            float vx = ve[3*p], vy = ve[3*p+1] - 9.8f * DT, vz = ve[3*p+2];
            float vv = sqrtf(vx*vx + vy*vy + vz*vz);
            float s  = fminf(MAX_VEL / (vv + 1e-4f), 1.0f);
            X[p] = lo[3*p]   + DT * vx * s;
            Y[p] = lo[3*p+1] + DT * vy * s;
            Z[p] = lo[3*p+2] + DT * vz * s;
        }
        sx[g] = make_float4(X[0], X[1], X[2], X[3]);
        sy[g] = make_float4(Y[0], Y[1], Y[2], Y[3]);
        sz[g] = make_float4(Z[0], Z[1], Z[2], Z[3]);
    }
}

// rho body: S_i = sum_j relu(R-d)^3 (self included); writes pre-scaled L = -3C*lam.
__device__ __forceinline__ void rho_body(const float4* sx, const float4* sy, const float4* sz,
                                         float* __restrict__ lam, int n4, int i, int lane) {
    const float* fx = (const float*)sx; const float* fy = (const float*)sy; const float* fz = (const float*)sz;
    const float xi = fx[i], yi = fy[i], zi = fz[i];
    float S = 0.f;
    for (int k = lane; k < n4; k += 64) {
        float4 X = sx[k], Y = sy[k], Z = sz[k];
#pragma unroll
        for (int c = 0; c < 4; ++c) {
            float dx = xi - elem(X,c), dy = yi - elem(Y,c), dz = zi - elem(Z,c);
            float d2 = fmaf(dx,dx,EPS); d2 = fmaf(dy,dy,d2); d2 = fmaf(dz,dz,d2);
            float t  = fmaxf(RADIUS - __builtin_amdgcn_sqrtf(d2), 0.f);
            S = fmaf(t*t, t, S);
        }
    }
    for (int off = 32; off > 0; off >>= 1) S += __shfl_down(S, off);
    if (lane == 0) {
        const float ts  = RADIUS - __builtin_amdgcn_sqrtf(EPS);  // exact self-term
        const float TS3 = ts*ts*ts;
        const float k3  = 3.f * SPIKY_C * STIFFNESS;             // L = -3C*lam
        lam[i] = k3 * (SPIKY_C * (S - TS3) - DENSITY_REST);
    }
}

// delta body: q_i = p_i + sum_j (L_i+L_j)*t^2/d * diff ; optional final outputs.
__device__ __forceinline__ void delta_body(const float4* sx, const float4* sy, const float4* sz,
                                           const float4* sl,
                                           float* __restrict__ qx, float* __restrict__ qy, float* __restrict__ qz,
                                           const float* __restrict__ locs,
                                           float* __restrict__ out_pred,
                                           float* __restrict__ vnx, float* __restrict__ vny, float* __restrict__ vnz,
                                           int n4, int i, int lane) {
    const float* fx = (const float*)sx; const float* fy = (const float*)sy;
    const float* fz = (const float*)sz; const float* fl = (const float*)sl;
    const float xi = fx[i], yi = fy[i], zi = fz[i], Li = fl[i];
    float ax = 0.f, ay = 0.f, az = 0.f;
    for (int k = lane; k < n4; k += 64) {
        float4 X = sx[k], Y = sy[k], Z = sz[k], L = sl[k];
#pragma unroll
        for (int c = 0; c < 4; ++c) {
            float dx = xi - elem(X,c), dy = yi - elem(Y,c), dz = zi - elem(Z,c);
            float d2 = fmaf(dx,dx,EPS); d2 = fmaf(dy,dy,d2); d2 = fmaf(dz,dz,d2);
            float rinv = __builtin_amdgcn_rsqf(d2);
            float t  = fmaxf(RADIUS - d2*rinv, 0.f);
            float cf = (Li + elem(L,c)) * (t*t) * rinv;
            ax = fmaf(cf, dx, ax); ay = fmaf(cf, dy, ay); az = fmaf(cf, dz, az);
        }
    }
    for (int off = 32; off > 0; off >>= 1) {
        ax += __shfl_down(ax, off); ay += __shfl_down(ay, off); az += __shfl_down(az, off);
    }
    if (lane == 0) {
        float nx_ = xi + ax, ny_ = yi + ay, nz_ = zi + az;
        qx[i] = nx_; qy[i] = ny_; qz[i] = nz_;
        if (out_pred) {
            out_pred[3*i+0] = nx_; out_pred[3*i+1] = ny_; out_pred[3*i+2] = nz_;
            vnx[i] = (nx_ - locs[3*i+0]) * (1.0f/DT);
            vny[i] = (ny_ - locs[3*i+1]) * (1.0f/DT);
            vnz[i] = (nz_ - locs[3*i+2]) * (1.0f/DT);
        }
    }
}

// ---------------- kernels: 512 threads (8 waves), 1 particle/wave ----------------

__global__ __launch_bounds__(512, 4) void k_rho_first(const float4* __restrict__ locs4,
                                                      const float4* __restrict__ vel4,
                                                      float* __restrict__ lam, int n) {
    __shared__ float4 sx[N4], sy[N4], sz[N4];   // 48 KB
    const int n4 = n >> 2;
    predict_to_lds(locs4, vel4, sx, sy, sz, n4, threadIdx.x, 512);
    __syncthreads();
    rho_body(sx, sy, sz, lam, n4, blockIdx.x * 8 + (threadIdx.x >> 6), threadIdx.x & 63);
}

__global__ __launch_bounds__(512, 4) void k_delta_first(const float4* __restrict__ locs4,
                                                        const float4* __restrict__ vel4,
                                                        const float4* __restrict__ Lm,
                                                        float* __restrict__ qx, float* __restrict__ qy,
                                                        float* __restrict__ qz, int n) {
    __shared__ float4 sx[N4], sy[N4], sz[N4], sl[N4];   // 64 KB
    const int n4 = n >> 2;
    predict_to_lds(locs4, vel4, sx, sy, sz, n4, threadIdx.x, 512);
    for (int idx = threadIdx.x; idx < n4; idx += 512) sl[idx] = Lm[idx];
    __syncthreads();
    delta_body(sx, sy, sz, sl, qx, qy, qz, nullptr, nullptr, nullptr, nullptr, nullptr,
               n4, blockIdx.x * 8 + (threadIdx.x >> 6), threadIdx.x & 63);
}

__global__ __launch_bounds__(512, 4) void k_rho(const float4* __restrict__ px, const float4* __restrict__ py,
                                                const float4* __restrict__ pz, float* __restrict__ lam, int n) {
    __shared__ float4 sx[N4], sy[N4], sz[N4];   // 48 KB
    const int n4 = n >> 2;
    for (int idx = threadIdx.x; idx < n4; idx += 512) {
        sx[idx] = px[idx]; sy[idx] = py[idx]; sz[idx] = pz[idx];
    }
    __syncthreads();
    rho_body(sx, sy, sz, lam, n4, blockIdx.x * 8 + (threadIdx.x >> 6), threadIdx.x & 63);
}

__global__ __launch_bounds__(512, 4) void k_delta(const float4* __restrict__ px, const float4* __restrict__ py,
                                                  const float4* __restrict__ pz, const float4* __restrict__ Lm,
                                                  float* __restrict__ qx, float* __restrict__ qy, float* __restrict__ qz,
                                                  const float* __restrict__ locs,
                                                  float* __restrict__ out_pred,
                                                  float* __restrict__ vnx, float* __restrict__ vny, float* __restrict__ vnz,
                                                  int n) {
    __shared__ float4 sx[N4], sy[N4], sz[N4], sl[N4];   // 64 KB
    const int n4 = n >> 2;
    for (int idx = threadIdx.x; idx < n4; idx += 512) {
        sx[idx] = px[idx]; sy[idx] = py[idx]; sz[idx] = pz[idx]; sl[idx] = Lm[idx];
    }
    __syncthreads();
    delta_body(sx, sy, sz, sl, qx, qy, qz, locs, out_pred, vnx, vny, vnz,
               n4, blockIdx.x * 8 + (threadIdx.x >> 6), threadIdx.x & 63);
}

__global__ __launch_bounds__(512, 4) void k_visc(const float4* __restrict__ px, const float4* __restrict__ py,
                                                 const float4* __restrict__ pz,
                                                 const float4* __restrict__ vx, const float4* __restrict__ vy,
                                                 const float4* __restrict__ vz,
                                                 float* __restrict__ out, int n) {
    __shared__ float4 cs[6][N4/2];   // 48 KB (2 chunks)
    const int wave = threadIdx.x >> 6, lane = threadIdx.x & 63;
    const int i = blockIdx.x * 8 + wave;
    const float* fpx = (const float*)px; const float* fpy = (const float*)py; const float* fpz = (const float*)pz;
    const float* fvx = (const float*)vx; const float* fvy = (const float*)vy; const float* fvz = (const float*)vz;
    const float xi = fpx[i], yi = fpy[i], zi = fpz[i];
    const float vix = fvx[i], viy = fvy[i], viz = fvz[i];
    float ws = 0.f, ax = 0.f, ay = 0.f, az = 0.f;
    const int n8 = n >> 3;  // chunk size in float4
    for (int ch = 0; ch < 2; ++ch) {
        __syncthreads();
        for (int idx = threadIdx.x; idx < n8; idx += 512) {
            cs[0][idx] = px[ch*n8+idx]; cs[1][idx] = py[ch*n8+idx]; cs[2][idx] = pz[ch*n8+idx];
            cs[3][idx] = vx[ch*n8+idx]; cs[4][idx] = vy[ch*n8+idx]; cs[5][idx] = vz[ch*n8+idx];
        }
        __syncthreads();
        for (int k = lane; k < n8; k += 64) {
            float4 X = cs[0][k], Y = cs[1][k], Z = cs[2][k];
            float4 VX = cs[3][k], VY = cs[4][k], VZ = cs[5][k];
#pragma unroll
            for (int c = 0; c < 4; ++c) {
                float dx = xi - elem(X,c), dy = yi - elem(Y,c), dz = zi - elem(Z,c);
                float d2 = fmaf(dx,dx,EPS); d2 = fmaf(dy,dy,d2); d2 = fmaf(dz,dz,d2);
                float t  = fmaxf(RADIUS - __builtin_amdgcn_sqrtf(d2), 0.f);
                float w  = t*t*t;
                ws += w;
                ax = fmaf(w, elem(VX,c), ax); ay = fmaf(w, elem(VY,c), ay); az = fmaf(w, elem(VZ,c), az);
            }
        }
    }
    for (int off = 32; off > 0; off >>= 1) {
        ws += __shfl_down(ws, off); ax += __shfl_down(ax, off);
        ay += __shfl_down(ay, off); az += __shfl_down(az, off);
    }
    if (lane == 0) {
        constexpr float K = VISCOSITY * DT / DENSITY_REST;
        const float KC = K * SPIKY_C;   // C folded here
        float nvx = vix + KC * (ax - ws * vix);
        float nvy = viy + KC * (ay - ws * viy);
        float nvz = viz + KC * (az - ws * viz);
        float vv = sqrtf(nvx*nvx + nvy*nvy + nvz*nvz);
        float s  = fminf(MAX_VEL / (vv + 1e-4f), 1.0f);
        out[3*n + 3*i + 0] = nvx * s;
        out[3*n + 3*i + 1] = nvy * s;
        out[3*n + 3*i + 2] = nvz * s;
    }
}

extern "C" void kernel_launch(void* const* d_in, const int* in_sizes, int n_in,
                              void* d_out, int out_size, void* d_ws, size_t ws_size,
                              hipStream_t stream) {
    const float* locs = (const float*)d_in[0];
    const float* vel  = (const float*)d_in[1];
    const float4* locs4 = (const float4*)locs;
    const float4* vel4  = (const float4*)vel;
    float* out = (float*)d_out;
    int n = in_sizes[0] / 3;

    float* w = (float*)d_ws;
    float* pAx = w;        float* pAy = pAx + n;  float* pAz = pAy + n;
    float* pBx = pAz + n;  float* pBy = pBx + n;  float* pBz = pBy + n;
    float* lam = pBz + n;
    float* vnx = lam + n;  float* vny = vnx + n;  float* vnz = vny + n;

    int nb = n / 8;   // 8 waves/block, 1 particle/wave

    // iteration 1 (pred recomputed in-block from locs/vel)
    k_rho_first<<<nb, 512, 0, stream>>>(locs4, vel4, lam, n);
    k_delta_first<<<nb, 512, 0, stream>>>(locs4, vel4, (const float4*)lam, pAx, pAy, pAz, n);
    // iteration 2: pA -> pB
    k_rho<<<nb, 512, 0, stream>>>((const float4*)pAx, (const float4*)pAy, (const float4*)pAz, lam, n);
    k_delta<<<nb, 512, 0, stream>>>((const float4*)pAx, (const float4*)pAy, (const float4*)pAz,
                                    (const float4*)lam, pBx, pBy, pBz,
                                    nullptr, nullptr, nullptr, nullptr, nullptr, n);
    // iteration 3: pB -> pA, emit pred + new_vel
    k_rho<<<nb, 512, 0, stream>>>((const float4*)pBx, (const float4*)pBy, (const float4*)pBz, lam, n);
    k_delta<<<nb, 512, 0, stream>>>((const float4*)pBx, (const float4*)pBy, (const float4*)pBz,
                                    (const float4*)lam, pAx, pAy, pAz,
                                    locs, out, vnx, vny, vnz, n);
    // XSPH viscosity on final positions
    k_visc<<<nb, 512, 0, stream>>>((const float4*)pAx, (const float4*)pAy, (const float4*)pAz,
                                   (const float4*)vnx, (const float4*)vny, (const float4*)vnz, out, n);
}

// Round 5
// 123.112 us; speedup vs baseline: 3.5535x; 1.0218x over previous
//
#include <hip/hip_runtime.h>
#include <math.h>

#define NMAX 4096
#define N4   (NMAX/4)

// n assumed multiple of 16 (reference: N=4096).

constexpr float RADIUS       = 0.1f;
constexpr float DT           = 1.0f / 60.0f;
constexpr float MAX_VEL      = 3.0f;               // 0.5*0.1/DT
constexpr float VISCOSITY    = 60.0f;
constexpr float DENSITY_REST = 17510.1f;
constexpr float STIFFNESS    = 2.99e-11f;
constexpr float EPS          = 1e-8f;
constexpr float SPIKY_C      = (float)(15.0 / (3.14159265358979323846 * 1e-6)); // 15/(pi*R^6)

__device__ __forceinline__ float elem(const float4& v, int c) {
    return reinterpret_cast<const float*>(&v)[c];
}

// Recompute predicted positions for the whole system into LDS (SoA float4).
__device__ __forceinline__ void predict_to_lds(const float4* __restrict__ locs4,
                                               const float4* __restrict__ vel4,
                                               float4* sx, float4* sy, float4* sz,
                                               int n4, int tid, int nthreads) {
    for (int g = tid; g < n4; g += nthreads) {
        float lo[12], ve[12];
        *(float4*)&lo[0] = locs4[3*g];   *(float4*)&lo[4] = locs4[3*g+1]; *(float4*)&lo[8] = locs4[3*g+2];
        *(float4*)&ve[0] = vel4[3*g];    *(float4*)&ve[4] = vel4[3*g+1];  *(float4*)&ve[8] = vel4[3*g+2];
        float X[4], Y[4], Z[4];
#pragma unroll
        for (int p = 0; p < 4; ++p) {
            float vx = ve[3*p], vy = ve[3*p+1] - 9.8f * DT, vz = ve[3*p+2];
            float vv = sqrtf(vx*vx + vy*vy + vz*vz);
            float s  = fminf(MAX_VEL / (vv + 1e-4f), 1.0f);
            X[p] = lo[3*p]   + DT * vx * s;
            Y[p] = lo[3*p+1] + DT * vy * s;
            Z[p] = lo[3*p+2] + DT * vz * s;
        }
        sx[g] = make_float4(X[0], X[1], X[2], X[3]);
        sy[g] = make_float4(Y[0], Y[1], Y[2], Y[3]);
        sz[g] = make_float4(Z[0], Z[1], Z[2], Z[3]);
    }
}

// rho body (2 particles/wave): writes pre-scaled L = -3C*lam for i0, i0+1.
__device__ __forceinline__ void rho_body2(const float4* sx, const float4* sy, const float4* sz,
                                          float* __restrict__ lam, int n4, int i0, int lane) {
    const float* fx = (const float*)sx; const float* fy = (const float*)sy; const float* fz = (const float*)sz;
    const float xi0 = fx[i0],   yi0 = fy[i0],   zi0 = fz[i0];
    const float xi1 = fx[i0+1], yi1 = fy[i0+1], zi1 = fz[i0+1];
    float S0 = 0.f, S1 = 0.f;
    for (int k = lane; k < n4; k += 64) {
        float4 X = sx[k], Y = sy[k], Z = sz[k];
#pragma unroll
        for (int c = 0; c < 4; ++c) {
            float xj = elem(X,c), yj = elem(Y,c), zj = elem(Z,c);
            {
                float dx = xi0-xj, dy = yi0-yj, dz = zi0-zj;
                float d2 = fmaf(dx,dx,EPS); d2 = fmaf(dy,dy,d2); d2 = fmaf(dz,dz,d2);
                float t  = fmaxf(RADIUS - __builtin_amdgcn_sqrtf(d2), 0.f);
                S0 = fmaf(t*t, t, S0);
            }
            {
                float dx = xi1-xj, dy = yi1-yj, dz = zi1-zj;
                float d2 = fmaf(dx,dx,EPS); d2 = fmaf(dy,dy,d2); d2 = fmaf(dz,dz,d2);
                float t  = fmaxf(RADIUS - __builtin_amdgcn_sqrtf(d2), 0.f);
                S1 = fmaf(t*t, t, S1);
            }
        }
    }
    for (int off = 32; off > 0; off >>= 1) {
        S0 += __shfl_down(S0, off);
        S1 += __shfl_down(S1, off);
    }
    if (lane == 0) {
        const float ts  = RADIUS - __builtin_amdgcn_sqrtf(EPS);  // exact self-term
        const float TS3 = ts*ts*ts;
        const float k3  = 3.f * SPIKY_C * STIFFNESS;             // L = -3C*lam
        lam[i0]   = k3 * (SPIKY_C * (S0 - TS3) - DENSITY_REST);
        lam[i0+1] = k3 * (SPIKY_C * (S1 - TS3) - DENSITY_REST);
    }
}

// delta body (2 particles/wave).
__device__ __forceinline__ void delta_body2(const float4* sx, const float4* sy, const float4* sz,
                                            const float4* sl,
                                            float* __restrict__ qx, float* __restrict__ qy, float* __restrict__ qz,
                                            const float* __restrict__ locs,
                                            float* __restrict__ out_pred,
                                            float* __restrict__ vnx, float* __restrict__ vny, float* __restrict__ vnz,
                                            int n4, int i0, int lane) {
    const float* fx = (const float*)sx; const float* fy = (const float*)sy;
    const float* fz = (const float*)sz; const float* fl = (const float*)sl;
    const float xi0 = fx[i0],   yi0 = fy[i0],   zi0 = fz[i0],   L0 = fl[i0];
    const float xi1 = fx[i0+1], yi1 = fy[i0+1], zi1 = fz[i0+1], L1 = fl[i0+1];
    float ax0=0.f, ay0=0.f, az0=0.f, ax1=0.f, ay1=0.f, az1=0.f;
    for (int k = lane; k < n4; k += 64) {
        float4 X = sx[k], Y = sy[k], Z = sz[k], L = sl[k];
#pragma unroll
        for (int c = 0; c < 4; ++c) {
            float xj = elem(X,c), yj = elem(Y,c), zj = elem(Z,c), Lj = elem(L,c);
            {
                float dx = xi0-xj, dy = yi0-yj, dz = zi0-zj;
                float d2 = fmaf(dx,dx,EPS); d2 = fmaf(dy,dy,d2); d2 = fmaf(dz,dz,d2);
                float rinv = __builtin_amdgcn_rsqf(d2);
                float t  = fmaxf(RADIUS - d2*rinv, 0.f);
                float cf = (L0 + Lj) * (t*t) * rinv;
                ax0 = fmaf(cf, dx, ax0); ay0 = fmaf(cf, dy, ay0); az0 = fmaf(cf, dz, az0);
            }
            {
                float dx = xi1-xj, dy = yi1-yj, dz = zi1-zj;
                float d2 = fmaf(dx,dx,EPS); d2 = fmaf(dy,dy,d2); d2 = fmaf(dz,dz,d2);
                float rinv = __builtin_amdgcn_rsqf(d2);
                float t  = fmaxf(RADIUS - d2*rinv, 0.f);
                float cf = (L1 + Lj) * (t*t) * rinv;
                ax1 = fmaf(cf, dx, ax1); ay1 = fmaf(cf, dy, ay1); az1 = fmaf(cf, dz, az1);
            }
        }
    }
    for (int off = 32; off > 0; off >>= 1) {
        ax0 += __shfl_down(ax0, off); ay0 += __shfl_down(ay0, off); az0 += __shfl_down(az0, off);
        ax1 += __shfl_down(ax1, off); ay1 += __shfl_down(ay1, off); az1 += __shfl_down(az1, off);
    }
    if (lane == 0) {
        float nx0 = xi0+ax0, ny0 = yi0+ay0, nz0 = zi0+az0;
        float nx1 = xi1+ax1, ny1 = yi1+ay1, nz1 = zi1+az1;
        qx[i0] = nx0; qy[i0] = ny0; qz[i0] = nz0;
        qx[i0+1] = nx1; qy[i0+1] = ny1; qz[i0+1] = nz1;
        if (out_pred) {
#pragma unroll
            for (int u = 0; u < 2; ++u) {
                int i = i0 + u;
                float nx_ = u ? nx1 : nx0, ny_ = u ? ny1 : ny0, nz_ = u ? nz1 : nz0;
                out_pred[3*i+0] = nx_; out_pred[3*i+1] = ny_; out_pred[3*i+2] = nz_;
                vnx[i] = (nx_ - locs[3*i+0]) * (1.0f/DT);
                vny[i] = (ny_ - locs[3*i+1]) * (1.0f/DT);
                vnz[i] = (nz_ - locs[3*i+2]) * (1.0f/DT);
            }
        }
    }
}

// ---------------- kernels: 256 blocks x 512 threads (8 waves), 2 particles/wave ----------------

__global__ __launch_bounds__(512, 4) void k_rho_first(const float4* __restrict__ locs4,
                                                      const float4* __restrict__ vel4,
                                                      float* __restrict__ lam, int n) {
    __shared__ float4 sx[N4], sy[N4], sz[N4];   // 48 KB
    const int n4 = n >> 2;
    predict_to_lds(locs4, vel4, sx, sy, sz, n4, threadIdx.x, 512);
    __syncthreads();
    rho_body2(sx, sy, sz, lam, n4, blockIdx.x * 16 + (threadIdx.x >> 6) * 2, threadIdx.x & 63);
}

__global__ __launch_bounds__(512, 4) void k_delta_first(const float4* __restrict__ locs4,
                                                        const float4* __restrict__ vel4,
                                                        const float4* __restrict__ Lm,
                                                        float* __restrict__ qx, float* __restrict__ qy,
                                                        float* __restrict__ qz, int n) {
    __shared__ float4 sx[N4], sy[N4], sz[N4], sl[N4];   // 64 KB
    const int n4 = n >> 2;
    predict_to_lds(locs4, vel4, sx, sy, sz, n4, threadIdx.x, 512);
    for (int idx = threadIdx.x; idx < n4; idx += 512) sl[idx] = Lm[idx];
    __syncthreads();
    delta_body2(sx, sy, sz, sl, qx, qy, qz, nullptr, nullptr, nullptr, nullptr, nullptr,
                n4, blockIdx.x * 16 + (threadIdx.x >> 6) * 2, threadIdx.x & 63);
}

__global__ __launch_bounds__(512, 4) void k_rho(const float4* __restrict__ px, const float4* __restrict__ py,
                                                const float4* __restrict__ pz, float* __restrict__ lam, int n) {
    __shared__ float4 sx[N4], sy[N4], sz[N4];   // 48 KB
    const int n4 = n >> 2;
    for (int idx = threadIdx.x; idx < n4; idx += 512) {
        sx[idx] = px[idx]; sy[idx] = py[idx]; sz[idx] = pz[idx];
    }
    __syncthreads();
    rho_body2(sx, sy, sz, lam, n4, blockIdx.x * 16 + (threadIdx.x >> 6) * 2, threadIdx.x & 63);
}

__global__ __launch_bounds__(512, 4) void k_delta(const float4* __restrict__ px, const float4* __restrict__ py,
                                                  const float4* __restrict__ pz, const float4* __restrict__ Lm,
                                                  float* __restrict__ qx, float* __restrict__ qy, float* __restrict__ qz,
                                                  const float* __restrict__ locs,
                                                  float* __restrict__ out_pred,
                                                  float* __restrict__ vnx, float* __restrict__ vny, float* __restrict__ vnz,
                                                  int n) {
    __shared__ float4 sx[N4], sy[N4], sz[N4], sl[N4];   // 64 KB
    const int n4 = n >> 2;
    for (int idx = threadIdx.x; idx < n4; idx += 512) {
        sx[idx] = px[idx]; sy[idx] = py[idx]; sz[idx] = pz[idx]; sl[idx] = Lm[idx];
    }
    __syncthreads();
    delta_body2(sx, sy, sz, sl, qx, qy, qz, locs, out_pred, vnx, vny, vnz,
                n4, blockIdx.x * 16 + (threadIdx.x >> 6) * 2, threadIdx.x & 63);
}

__global__ __launch_bounds__(512, 4) void k_visc(const float4* __restrict__ px, const float4* __restrict__ py,
                                                 const float4* __restrict__ pz,
                                                 const float4* __restrict__ vx, const float4* __restrict__ vy,
                                                 const float4* __restrict__ vz,
                                                 float* __restrict__ out, int n) {
    __shared__ float4 cs[6][N4/2];   // 48 KB (2 chunks)
    const int wave = threadIdx.x >> 6, lane = threadIdx.x & 63;
    const int i0 = blockIdx.x * 16 + wave * 2;
    const float* fpx = (const float*)px; const float* fpy = (const float*)py; const float* fpz = (const float*)pz;
    const float* fvx = (const float*)vx; const float* fvy = (const float*)vy; const float* fvz = (const float*)vz;
    const float xi0 = fpx[i0],   yi0 = fpy[i0],   zi0 = fpz[i0];
    const float xi1 = fpx[i0+1], yi1 = fpy[i0+1], zi1 = fpz[i0+1];
    const float vix0 = fvx[i0],   viy0 = fvy[i0],   viz0 = fvz[i0];
    const float vix1 = fvx[i0+1], viy1 = fvy[i0+1], viz1 = fvz[i0+1];
    float ws0=0.f, ax0=0.f, ay0=0.f, az0=0.f;
    float ws1=0.f, ax1=0.f, ay1=0.f, az1=0.f;
    const int n8 = n >> 3;  // chunk size in float4
    for (int ch = 0; ch < 2; ++ch) {
        __syncthreads();
        for (int idx = threadIdx.x; idx < n8; idx += 512) {
            cs[0][idx] = px[ch*n8+idx]; cs[1][idx] = py[ch*n8+idx]; cs[2][idx] = pz[ch*n8+idx];
            cs[3][idx] = vx[ch*n8+idx]; cs[4][idx] = vy[ch*n8+idx]; cs[5][idx] = vz[ch*n8+idx];
        }
        __syncthreads();
        for (int k = lane; k < n8; k += 64) {
            float4 X = cs[0][k], Y = cs[1][k], Z = cs[2][k];
            float4 VX = cs[3][k], VY = cs[4][k], VZ = cs[5][k];
#pragma unroll
            for (int c = 0; c < 4; ++c) {
                float xj = elem(X,c), yj = elem(Y,c), zj = elem(Z,c);
                float vxj = elem(VX,c), vyj = elem(VY,c), vzj = elem(VZ,c);
                {
                    float dx = xi0-xj, dy = yi0-yj, dz = zi0-zj;
                    float d2 = fmaf(dx,dx,EPS); d2 = fmaf(dy,dy,d2); d2 = fmaf(dz,dz,d2);
                    float t  = fmaxf(RADIUS - __builtin_amdgcn_sqrtf(d2), 0.f);
                    float w  = t*t*t;
                    ws0 += w;
                    ax0 = fmaf(w, vxj, ax0); ay0 = fmaf(w, vyj, ay0); az0 = fmaf(w, vzj, az0);
                }
                {
                    float dx = xi1-xj, dy = yi1-yj, dz = zi1-zj;
                    float d2 = fmaf(dx,dx,EPS); d2 = fmaf(dy,dy,d2); d2 = fmaf(dz,dz,d2);
                    float t  = fmaxf(RADIUS - __builtin_amdgcn_sqrtf(d2), 0.f);
                    float w  = t*t*t;
                    ws1 += w;
                    ax1 = fmaf(w, vxj, ax1); ay1 = fmaf(w, vyj, ay1); az1 = fmaf(w, vzj, az1);
                }
            }
        }
    }
    for (int off = 32; off > 0; off >>= 1) {
        ws0 += __shfl_down(ws0, off); ax0 += __shfl_down(ax0, off);
        ay0 += __shfl_down(ay0, off); az0 += __shfl_down(az0, off);
        ws1 += __shfl_down(ws1, off); ax1 += __shfl_down(ax1, off);
        ay1 += __shfl_down(ay1, off); az1 += __shfl_down(az1, off);
    }
    if (lane == 0) {
        constexpr float K = VISCOSITY * DT / DENSITY_REST;
        const float KC = K * SPIKY_C;   // C folded here
#pragma unroll
        for (int u = 0; u < 2; ++u) {
            int i = i0 + u;
            float vix = (u ? vix1 : vix0), viy = (u ? viy1 : viy0), viz = (u ? viz1 : viz0);
            float sw  = (u ? ws1 : ws0);
            float sax = (u ? ax1 : ax0), say = (u ? ay1 : ay0), saz = (u ? az1 : az0);
            float nvx = vix + KC * (sax - sw * vix);
            float nvy = viy + KC * (say - sw * viy);
            float nvz = viz + KC * (saz - sw * viz);
            float vv = sqrtf(nvx*nvx + nvy*nvy + nvz*nvz);
            float s  = fminf(MAX_VEL / (vv + 1e-4f), 1.0f);
            out[3*n + 3*i + 0] = nvx * s;
            out[3*n + 3*i + 1] = nvy * s;
            out[3*n + 3*i + 2] = nvz * s;
        }
    }
}

extern "C" void kernel_launch(void* const* d_in, const int* in_sizes, int n_in,
                              void* d_out, int out_size, void* d_ws, size_t ws_size,
                              hipStream_t stream) {
    const float* locs = (const float*)d_in[0];
    const float* vel  = (const float*)d_in[1];
    const float4* locs4 = (const float4*)locs;
    const float4* vel4  = (const float4*)vel;
    float* out = (float*)d_out;
    int n = in_sizes[0] / 3;

    float* w = (float*)d_ws;
    float* pAx = w;        float* pAy = pAx + n;  float* pAz = pAy + n;
    float* pBx = pAz + n;  float* pBy = pBx + n;  float* pBz = pBy + n;
    float* lam = pBz + n;
    float* vnx = lam + n;  float* vny = vnx + n;  float* vnz = vny + n;

    int nb = n / 16;   // 8 waves/block, 2 particles/wave

    // iteration 1 (pred recomputed in-block from locs/vel)
    k_rho_first<<<nb, 512, 0, stream>>>(locs4, vel4, lam, n);
    k_delta_first<<<nb, 512, 0, stream>>>(locs4, vel4, (const float4*)lam, pAx, pAy, pAz, n);
    // iteration 2: pA -> pB
    k_rho<<<nb, 512, 0, stream>>>((const float4*)pAx, (const float4*)pAy, (const float4*)pAz, lam, n);
    k_delta<<<nb, 512, 0, stream>>>((const float4*)pAx, (const float4*)pAy, (const float4*)pAz,
                                    (const float4*)lam, pBx, pBy, pBz,
                                    nullptr, nullptr, nullptr, nullptr, nullptr, n);
    // iteration 3: pB -> pA, emit pred + new_vel
    k_rho<<<nb, 512, 0, stream>>>((const float4*)pBx, (const float4*)pBy, (const float4*)pBz, lam, n);
    k_delta<<<nb, 512, 0, stream>>>((const float4*)pBx, (const float4*)pBy, (const float4*)pBz,
                                    (const float4*)lam, pAx, pAy, pAz,
                                    locs, out, vnx, vny, vnz, n);
    // XSPH viscosity on final positions
    k_visc<<<nb, 512, 0, stream>>>((const float4*)pAx, (const float4*)pAy, (const float4*)pAz,
                                   (const float4*)vnx, (const float4*)vny, (const float4*)vnz, out, n);
}